// Round 6
// baseline (87.838 us; speedup 1.0000x reference)
//
#include <hip/hip_runtime.h>
#include <hip/hip_bf16.h>

typedef short short8 __attribute__((ext_vector_type(8)));
typedef short short4v __attribute__((ext_vector_type(4)));
typedef float f32x4 __attribute__((ext_vector_type(4)));
typedef float f32x16 __attribute__((ext_vector_type(16)));

#define HID 4096
#define CST 68   // f32 LDS row stride for cayley kernel

__device__ __forceinline__ unsigned short f2bf(float f) {
    unsigned int u = __float_as_uint(f);
    u = (u + 0x7FFFu + ((u >> 16) & 1u)) >> 16;
    return (unsigned short)u;
}

// f32x4 = row i of SA (64x64, stride CST) times SB columns j0..j0+3
__device__ __forceinline__ f32x4 mm4(const float* SA, const float* SB, int i, int j0) {
    f32x4 acc = {0.f, 0.f, 0.f, 0.f};
#pragma unroll 8
    for (int k = 0; k < 64; ++k) {
        float a = SA[i * CST + k];
        acc += a * *reinterpret_cast<const f32x4*>(SB + k * CST + j0);
    }
    return acc;
}

// ---------- Kernel 1: Cayley (Neumann product form) + M-build, fused ----------
__global__ __launch_bounds__(1024) void cayley_build_kernel(
    const float* __restrict__ rul, const float* __restrict__ rvl, const float* __restrict__ dl,
    const float* __restrict__ rur, const float* __restrict__ rvr, const float* __restrict__ dr,
    const int* __restrict__ invt,
    unsigned short* __restrict__ plb, unsigned short* __restrict__ mrtb)
{
    __shared__ __align__(16) float Yw[64 * CST], Aw[64 * CST], Pw[64 * CST];
    __shared__ __align__(16) float Qw[64 * CST], QTw[64 * CST];
    __shared__ float dd[64];

    const float* ru; const float* rv; const float* dv; unsigned short* ob;
    if (blockIdx.x == 0) { ru = rul; rv = rvl; dv = dl; ob = plb; }
    else                 { ru = rur; rv = rvr; dv = dr; ob = mrtb; }

    const int tid = threadIdx.x;
    const int i = tid >> 4;
    const int j0 = (tid & 15) << 2;

    for (int pass = 0; pass < 2; ++pass) {
        const float* raw = (pass == 0) ? ru : rv;
#pragma unroll
        for (int q = 0; q < 4; ++q) {
            int j = j0 + q;
            float v = 0.f;
            if (j > i)      v =  raw[i * 64 + j];
            else if (j < i) v = -raw[j * 64 + i];
            Yw[i * CST + j] = 0.5f * v;
        }
        __syncthreads();
        f32x4 a = mm4(Yw, Yw, i, j0);                    // A = Y*Y
        __syncthreads();
        *reinterpret_cast<f32x4*>(Aw + i * CST + j0) = a;
        *reinterpret_cast<f32x4*>(Pw + i * CST + j0) =   // P = Y + A
            a + *reinterpret_cast<const f32x4*>(Yw + i * CST + j0);
        __syncthreads();
        a = mm4(Pw, Aw, i, j0);                          // P += P*A
        __syncthreads();
        *reinterpret_cast<f32x4*>(Pw + i * CST + j0) += a;
        __syncthreads();
        a = mm4(Aw, Aw, i, j0);                          // A = A*A
        __syncthreads();
        *reinterpret_cast<f32x4*>(Aw + i * CST + j0) = a;
        __syncthreads();
        a = mm4(Pw, Aw, i, j0);                          // P += P*A
        __syncthreads();
        f32x4 p = *reinterpret_cast<const f32x4*>(Pw + i * CST + j0) + a;
#pragma unroll
        for (int q = 0; q < 4; ++q) {
            int j = j0 + q;
            float qv = ((i == j) ? 1.f : 0.f) + 2.f * p[q];
            if (pass == 0) Qw[i * CST + j]  = qv;   // Qu[i][j]
            else           QTw[j * CST + i] = qv;   // Qv^T
        }
        __syncthreads();
    }
    if (tid < 64) { float d = dv[tid]; dd[tid] = (invt[0] != 0) ? (1.0f / d) : d; }
    __syncthreads();

    f32x4 m = {0.f, 0.f, 0.f, 0.f};
#pragma unroll 8
    for (int j = 0; j < 64; ++j) {
        float aa = Qw[i * CST + j] * dd[j];
        m += aa * *reinterpret_cast<const f32x4*>(QTw + j * CST + j0);
    }
#pragma unroll
    for (int q = 0; q < 4; ++q)
        ob[(j0 + q) * 64 + i] = f2bf(m[q]);
}

// ---------- Kernel 2: coalesced-I/O kron, 1 token/wave, 32x32x16 MFMA ----------
// Wave-private 8KB LDS tile, chunk-XOR swizzled (16B chunks; slot = c ^ (row&7)).
// Phase A: coalesced f32 loads -> (x*ds) -> bf16 tile Xs.
// Phase B: Z = Xs*MR  (A from LDS, B = MR^T rows from L1).
// Phase C: Zt = Z^T overwrites the tile (b64 fragment writes).
// Phase D: Out = PL*Z (A = PL rows from L1, B from LDS); stores write two
//          full 128B lines per instruction (D-layout col = lane&31).
__global__ __launch_bounds__(256, 4) void kron_kernel(
    const float* __restrict__ inp, const float* __restrict__ ds,
    const unsigned short* __restrict__ plb, const unsigned short* __restrict__ mrtb,
    const int* __restrict__ invt, float* __restrict__ out, int ntok)
{
    __shared__ __align__(16) unsigned char sbuf[4][8192];
    const int w = threadIdx.x >> 6;
    const int lane = threadIdx.x & 63;
    const int r = lane & 31;      // row/col within 32-tile
    const int h = lane >> 5;      // k-half
    unsigned char* S = sbuf[w];

    const int t = blockIdx.x * 4 + w;
    if (t >= ntok) return;
    const bool inv = (invt[0] != 0);

    // ---- Phase A: stage token, fully coalesced (2KB contiguous per step) ----
    const float* xt = inp + (size_t)t * HID;
    const int c = lane & 7;          // chunk within row
    const int mr0 = lane >> 3;       // row within span
#pragma unroll
    for (int s = 0; s < 8; ++s) {
        const int fi = s * 512 + lane * 8;
        f32x4 x0 = *reinterpret_cast<const f32x4*>(xt + fi);
        f32x4 x1 = *reinterpret_cast<const f32x4*>(xt + fi + 4);
        f32x4 d0 = *reinterpret_cast<const f32x4*>(ds + fi);
        f32x4 d1 = *reinterpret_cast<const f32x4*>(ds + fi + 4);
        if (inv) {
#pragma unroll
            for (int e = 0; e < 4; ++e) { x0[e] /= d0[e]; x1[e] /= d1[e]; }
        } else {
            x0 *= d0; x1 *= d1;
        }
        short8 f;
#pragma unroll
        for (int e = 0; e < 4; ++e) {
            f[e]     = (short)f2bf(x0[e]);
            f[e + 4] = (short)f2bf(x1[e]);
        }
        const int m = s * 8 + mr0;
        *reinterpret_cast<short8*>(S + ((m * 8 + (c ^ (m & 7))) << 4)) = f;
    }
    asm volatile("s_waitcnt lgkmcnt(0)" ::: "memory");
    __builtin_amdgcn_sched_barrier(0);

    // ---- Phase B: A1 fragments (LDS) + B1 fragments (MR^T, L1) ----
    short8 a1[2][4];
#pragma unroll
    for (int mt = 0; mt < 2; ++mt)
#pragma unroll
        for (int kt = 0; kt < 4; ++kt)
            a1[mt][kt] = *reinterpret_cast<const short8*>(
                S + (((32 * mt + r) * 8 + ((2 * kt + h) ^ (r & 7))) << 4));
    short8 b1[4][2];
#pragma unroll
    for (int kt = 0; kt < 4; ++kt)
#pragma unroll
        for (int nt = 0; nt < 2; ++nt)
            b1[kt][nt] = *reinterpret_cast<const short8*>(
                (const short*)mrtb + (32 * nt + r) * 64 + 16 * kt + 8 * h);

    asm volatile("s_waitcnt lgkmcnt(0)" ::: "memory");
    __builtin_amdgcn_sched_barrier(0);

    // ---- mfma1 per tile, then write Z^T fragment into the same LDS tile ----
#pragma unroll
    for (int mt = 0; mt < 2; ++mt)
#pragma unroll
        for (int nt = 0; nt < 2; ++nt) {
            f32x16 acc = {0.f};
#pragma unroll
            for (int kt = 0; kt < 4; ++kt)
                acc = __builtin_amdgcn_mfma_f32_32x32x16_bf16(a1[mt][kt], b1[kt][nt], acc, 0, 0, 0);
            // lane holds Z[rows][32nt+r]; write Zt[l=32nt+r][j] quads
            const int l = 32 * nt + r;
#pragma unroll
            for (int q = 0; q < 4; ++q) {
                short4v zz;
#pragma unroll
                for (int e = 0; e < 4; ++e) zz[e] = (short)f2bf(acc[4 * q + e]);
                *reinterpret_cast<short4v*>(
                    S + (((l * 8 + ((4 * mt + q) ^ (l & 7))) << 4) + 8 * h)) = zz;
            }
        }
    asm volatile("s_waitcnt lgkmcnt(0)" ::: "memory");
    __builtin_amdgcn_sched_barrier(0);

    // ---- Phase D: Out = PL * Z ----
    short8 b2[4][2];
#pragma unroll
    for (int kt = 0; kt < 4; ++kt)
#pragma unroll
        for (int nt = 0; nt < 2; ++nt)
            b2[kt][nt] = *reinterpret_cast<const short8*>(
                S + (((32 * nt + r) * 8 + ((2 * kt + h) ^ (r & 7))) << 4));
    short8 a2[2][4];
#pragma unroll
    for (int mt = 0; mt < 2; ++mt)
#pragma unroll
        for (int kt = 0; kt < 4; ++kt)
            a2[mt][kt] = *reinterpret_cast<const short8*>(
                (const short*)plb + (32 * mt + r) * 64 + 16 * kt + 8 * h);

    float* op = out + (size_t)t * HID;
#pragma unroll
    for (int mt = 0; mt < 2; ++mt)
#pragma unroll
        for (int nt = 0; nt < 2; ++nt) {
            f32x16 acc = {0.f};
#pragma unroll
            for (int kt = 0; kt < 4; ++kt)
                acc = __builtin_amdgcn_mfma_f32_32x32x16_bf16(a2[mt][kt], b2[kt][nt], acc, 0, 0, 0);
            // D: col = 32nt + r, row k = 32mt + (reg&3) + 8*(reg>>2) + 4h
#pragma unroll
            for (int g = 0; g < 16; ++g) {
                const int k = 32 * mt + (g & 3) + 8 * (g >> 2) + 4 * h;
                op[k * 64 + 32 * nt + r] = acc[g];
            }
        }
}

extern "C" void kernel_launch(void* const* d_in, const int* in_sizes, int n_in,
                              void* d_out, int out_size, void* d_ws, size_t ws_size,
                              hipStream_t stream) {
    const float* inp = (const float*)d_in[0];
    const float* rul = (const float*)d_in[1];
    const float* rvl = (const float*)d_in[2];
    const float* dl  = (const float*)d_in[3];
    const float* rur = (const float*)d_in[4];
    const float* rvr = (const float*)d_in[5];
    const float* dr  = (const float*)d_in[6];
    const float* ds  = (const float*)d_in[7];
    const int*   invt = (const int*)d_in[8];
    float* out = (float*)d_out;

    unsigned short* plb  = (unsigned short*)d_ws;   // 4096 bf16 (PL = ML^T, row-major)
    unsigned short* mrtb = plb + 4096;              // 4096 bf16 (MR^T, row-major)

    const int ntok = in_sizes[0] / HID;

    hipLaunchKernelGGL(cayley_build_kernel, dim3(2), dim3(1024), 0, stream,
                       rul, rvl, dl, rur, rvr, dr, invt, plb, mrtb);
    const int nblk = (ntok + 3) / 4;
    hipLaunchKernelGGL(kron_kernel, dim3(nblk), dim3(256), 0, stream,
                       inp, ds, plb, mrtb, invt, out, ntok);
}